// Round 6
// baseline (23.612 us; speedup 1.0000x reference)
//
#include <hip/hip_runtime.h>
#include <math.h>

// ForwardKinematics: B graphs x 24 joints, fixed tree (compile-time).
// PERSISTENT 2-TILE blocks: 512 blocks (2/CU), each handles two 64-graph tiles.
// Tile-1's global loads are issued into registers right after tile-0's LDS
// staging (register WAR only), so ~55 KB/block of tile-1 traffic is in flight
// under tile-0's compute+flush -> memory pipe never idles (fixes R4's duty
// cycle; R4 = 21.6us vs 12us compulsory-BW floor).
// Per-tile structure is R4's verified one:
//   4 waves, lane t = graph. w0: 0,1-4,22,23  w1: 5-8  w2: 9-13 (publishes
//   R11/P11/R12/P12)  w3: 14-21.
// LDS arena (62.4 KB), alias-free:
//   rows   0..143 XS (immutable per tile), 144..215 OS/OUTS (same-joint alias,
//   same-wave program order only), 216..239 HF (exclusive handoff region).

#define PAD 65
#define G   64

#define XS(f,g)   arena[(f)*PAD + (g)]
#define OS(f,g)   arena[(144+(f))*PAD + (g)]
#define OUTS(r,g) arena[(144+(r))*PAD + (g)]
#define HF(r,g)   arena[(216+(r))*PAD + (g)]

__device__ __forceinline__ void rot6d(const float a[6], float T[9]) {
    float n1 = sqrtf(a[0]*a[0] + a[1]*a[1] + a[2]*a[2]) + 1e-12f;
    float i1 = 1.0f / n1;
    float b1x = a[0]*i1, b1y = a[1]*i1, b1z = a[2]*i1;
    float d = b1x*a[3] + b1y*a[4] + b1z*a[5];
    float ax = a[3] - d*b1x, ay = a[4] - d*b1y, az = a[5] - d*b1z;
    float n2 = sqrtf(ax*ax + ay*ay + az*az) + 1e-12f;
    float i2 = 1.0f / n2;
    float b2x = ax*i2, b2y = ay*i2, b2z = az*i2;
    T[0] = b1x; T[1] = b1y; T[2] = b1z;
    T[3] = b2x; T[4] = b2y; T[5] = b2z;
    T[6] = b1y*b2z - b1z*b2y;
    T[7] = b1z*b2x - b1x*b2z;
    T[8] = b1x*b2y - b1y*b2x;
}

template<int J>
__device__ __forceinline__ void pullX(const float* arena, int t, float T[9]) {
    float a[6];
#pragma unroll
    for (int c = 0; c < 6; ++c) a[c] = XS(6*J+c, t);
    rot6d(a, T);
}

template<int J>
__device__ __forceinline__ void pull(const float* arena, int t, float T[9], float o[3]) {
    float a[6];
#pragma unroll
    for (int c = 0; c < 6; ++c) a[c] = XS(6*J+c, t);
#pragma unroll
    for (int c = 0; c < 3; ++c) o[c] = OS(3*J+c, t);
    rot6d(a, T);
}

template<int J>
__device__ __forceinline__ void chain_step(float* arena, int t, float R[9], float P[3],
                                           const float T[9], const float o[3]) {
    float p0 = R[0]*o[0] + R[1]*o[1] + R[2]*o[2] + P[0];
    float p1 = R[3]*o[0] + R[4]*o[1] + R[5]*o[2] + P[1];
    float p2 = R[6]*o[0] + R[7]*o[1] + R[8]*o[2] + P[2];
    float Rn[9];
#pragma unroll
    for (int i = 0; i < 3; ++i)
#pragma unroll
        for (int k = 0; k < 3; ++k)
            Rn[i*3+k] = R[i*3+0]*T[0+k] + R[i*3+1]*T[3+k] + R[i*3+2]*T[6+k];
#pragma unroll
    for (int i = 0; i < 9; ++i) R[i] = Rn[i];
    P[0] = p0; P[1] = p1; P[2] = p2;
    OUTS(3*J+0, t) = p0; OUTS(3*J+1, t) = p1; OUTS(3*J+2, t) = p2;
}

__device__ __forceinline__ void load_regs(const float4* __restrict__ x4,
                                          const float2* __restrict__ o2,
                                          long tile, int tid,
                                          float4 xr[9], float2 orr[9]) {
    long gb0 = tile * G;
#pragma unroll
    for (int k = 0; k < 9; ++k) xr[k]  = x4[gb0*36 + k*256 + tid];
#pragma unroll
    for (int k = 0; k < 9; ++k) orr[k] = o2[gb0*36 + k*256 + tid];
}

__device__ __forceinline__ void stage_lds(float* arena, int tid,
                                          const float4 xr[9], const float2 orr[9]) {
#pragma unroll
    for (int k = 0; k < 9; ++k) {
        int i = k*256 + tid; int g = i/36, e = i - g*36;
        XS(4*e+0, g) = xr[k].x; XS(4*e+1, g) = xr[k].y;
        XS(4*e+2, g) = xr[k].z; XS(4*e+3, g) = xr[k].w;
    }
#pragma unroll
    for (int k = 0; k < 9; ++k) {
        int i = k*256 + tid; int g = i/36, e = i - g*36;
        OS(2*e+0, g) = orr[k].x; OS(2*e+1, g) = orr[k].y;
    }
}

// Full per-tile compute: phase1 + sync_a + phase2. Caller barriers around it.
__device__ __forceinline__ void compute_tile(float* arena, int w, int t) {
    float Ta[8][9], oa[8][3];
    float R[9], P[3];
    if (w == 0) {
        pullX<0>(arena, t, R);
        pull<1>(arena, t, Ta[0], oa[0]);
        pull<2>(arena, t, Ta[1], oa[1]);
        pull<3>(arena, t, Ta[2], oa[2]);
        pull<4>(arena, t, Ta[3], oa[3]);
        pull<22>(arena, t, Ta[4], oa[4]);
        pull<23>(arena, t, Ta[5], oa[5]);
        P[0] = P[1] = P[2] = 0.0f;
        OUTS(0, t) = 0.0f; OUTS(1, t) = 0.0f; OUTS(2, t) = 0.0f;
        chain_step<1>(arena, t, R, P, Ta[0], oa[0]);
        chain_step<2>(arena, t, R, P, Ta[1], oa[1]);
        chain_step<3>(arena, t, R, P, Ta[2], oa[2]);
        chain_step<4>(arena, t, R, P, Ta[3], oa[3]);
    } else if (w == 1) {
        pullX<0>(arena, t, R);
        pull<5>(arena, t, Ta[0], oa[0]);
        pull<6>(arena, t, Ta[1], oa[1]);
        pull<7>(arena, t, Ta[2], oa[2]);
        pull<8>(arena, t, Ta[3], oa[3]);
        P[0] = P[1] = P[2] = 0.0f;
        chain_step<5>(arena, t, R, P, Ta[0], oa[0]);
        chain_step<6>(arena, t, R, P, Ta[1], oa[1]);
        chain_step<7>(arena, t, R, P, Ta[2], oa[2]);
        chain_step<8>(arena, t, R, P, Ta[3], oa[3]);
    } else if (w == 2) {
        pullX<0>(arena, t, R);
        pull<9> (arena, t, Ta[0], oa[0]);
        pull<10>(arena, t, Ta[1], oa[1]);
        pull<11>(arena, t, Ta[2], oa[2]);
        pull<12>(arena, t, Ta[3], oa[3]);
        pull<13>(arena, t, Ta[4], oa[4]);
        P[0] = P[1] = P[2] = 0.0f;
        chain_step<9> (arena, t, R, P, Ta[0], oa[0]);
        chain_step<10>(arena, t, R, P, Ta[1], oa[1]);
        chain_step<11>(arena, t, R, P, Ta[2], oa[2]);
#pragma unroll
        for (int i = 0; i < 9; ++i) HF(i, t) = R[i];        // R11
#pragma unroll
        for (int c = 0; c < 3; ++c) HF(9+c, t) = P[c];      // P11
        chain_step<12>(arena, t, R, P, Ta[3], oa[3]);
#pragma unroll
        for (int i = 0; i < 9; ++i) HF(12+i, t) = R[i];     // R12
#pragma unroll
        for (int c = 0; c < 3; ++c) HF(21+c, t) = P[c];     // P12
        chain_step<13>(arena, t, R, P, Ta[4], oa[4]);
    } else {
        pull<14>(arena, t, Ta[0], oa[0]);
        pull<15>(arena, t, Ta[1], oa[1]);
        pull<16>(arena, t, Ta[2], oa[2]);
        pull<17>(arena, t, Ta[3], oa[3]);
        pull<18>(arena, t, Ta[4], oa[4]);
        pull<19>(arena, t, Ta[5], oa[5]);
        pull<20>(arena, t, Ta[6], oa[6]);
        pull<21>(arena, t, Ta[7], oa[7]);
    }
    __syncthreads();                         // sync_a: R11/P11/R12/P12 published
    if (w == 0) {
#pragma unroll
        for (int i = 0; i < 9; ++i) R[i] = HF(12+i, t);
#pragma unroll
        for (int c = 0; c < 3; ++c) P[c] = HF(21+c, t);
        chain_step<22>(arena, t, R, P, Ta[4], oa[4]);
        chain_step<23>(arena, t, R, P, Ta[5], oa[5]);
    } else if (w == 3) {
#pragma unroll
        for (int i = 0; i < 9; ++i) R[i] = HF(i, t);
#pragma unroll
        for (int c = 0; c < 3; ++c) P[c] = HF(9+c, t);
        chain_step<14>(arena, t, R, P, Ta[0], oa[0]);
        chain_step<15>(arena, t, R, P, Ta[1], oa[1]);
        chain_step<16>(arena, t, R, P, Ta[2], oa[2]);
        chain_step<17>(arena, t, R, P, Ta[3], oa[3]);
#pragma unroll
        for (int i = 0; i < 9; ++i) R[i] = HF(i, t);
#pragma unroll
        for (int c = 0; c < 3; ++c) P[c] = HF(9+c, t);
        chain_step<18>(arena, t, R, P, Ta[4], oa[4]);
        chain_step<19>(arena, t, R, P, Ta[5], oa[5]);
        chain_step<20>(arena, t, R, P, Ta[6], oa[6]);
        chain_step<21>(arena, t, R, P, Ta[7], oa[7]);
    }
}

__device__ __forceinline__ void flush_tile(const float* arena, float4* __restrict__ out4,
                                           long tile, int tid) {
    long gb0 = tile * G;
#pragma unroll
    for (int k = 0; k < 5; ++k) {
        int i = k*256 + tid;
        if (i < 1152) {
            int g = i/18, e = i - g*18;
            float4 v;
            v.x = OUTS(4*e+0, g); v.y = OUTS(4*e+1, g);
            v.z = OUTS(4*e+2, g); v.w = OUTS(4*e+3, g);
            out4[gb0*18 + i] = v;
        }
    }
}

__global__ __launch_bounds__(256, 2) void fk_kernel(const float* __restrict__ x,
                                                    const float* __restrict__ off,
                                                    float* __restrict__ out,
                                                    int ntiles) {
    __shared__ float arena[240 * PAD];   // 62400 B
    const int tid = threadIdx.x;
    const int w = tid >> 6;
    const int t = tid & 63;
    const float4* x4 = (const float4*)x;
    const float2* o2 = (const float2*)off;
    float4* out4 = (float4*)out;

    long tile0 = (long)blockIdx.x * 2;
    long tile1 = tile0 + 1;
    bool has2 = (tile1 < ntiles);

    float4 xr[9]; float2 orr[9];

    // ---- tile 0: load -> stage ----
    load_regs(x4, o2, tile0, tid, xr, orr);
    stage_lds(arena, tid, xr, orr);
    // ---- prefetch tile 1 into the same registers (WAR only; in flight
    //      throughout tile-0 compute + flush) ----
    if (has2) load_regs(x4, o2, tile1, tid, xr, orr);
    __syncthreads();                         // sync0: tile0 staged

    compute_tile(arena, w, t);
    __syncthreads();                         // sync_b: OUTS final
    flush_tile(arena, out4, tile0, tid);

    if (has2) {
        __syncthreads();                     // sync_c: flush LDS-reads done
        stage_lds(arena, tid, xr, orr);      // waits on prefetched loads
        __syncthreads();                     // sync0': tile1 staged
        compute_tile(arena, w, t);
        __syncthreads();                     // sync_b'
        flush_tile(arena, out4, tile1, tid);
    }
}

// Fallback (per-thread whole graph) for B not divisible by 64 — not expected here.
__global__ __launch_bounds__(256) void fk_tail(const float* __restrict__ x,
                                               const float* __restrict__ off,
                                               float* __restrict__ out,
                                               int b0, int B) {
    int b = b0 + blockIdx.x * blockDim.x + threadIdx.x;
    if (b >= B) return;
    const float* xb = x + (size_t)b * 144;
    const float* ob = off + (size_t)b * 72;
    float* P = out + (size_t)b * 72;
    float R[9], Pc[3], R0[9], R11[9], P11[3], R12[9], P12[3];
    {
        float a[6] = {xb[0],xb[1],xb[2],xb[3],xb[4],xb[5]};
        rot6d(a, R);
        Pc[0] = Pc[1] = Pc[2] = 0.0f;
        P[0] = P[1] = P[2] = 0.0f;
        for (int i = 0; i < 9; ++i) R0[i] = R[i];
    }
    for (int j = 1; j < 24; ++j) {
        float Rp[9], Pp[3];
        if (j==1||j==5||j==9) { for (int i=0;i<9;++i) Rp[i]=R0[i]; Pp[0]=Pp[1]=Pp[2]=0.f; }
        else if (j==14||j==18) { for (int i=0;i<9;++i) Rp[i]=R11[i]; Pp[0]=P11[0];Pp[1]=P11[1];Pp[2]=P11[2]; }
        else if (j==22)   { for (int i=0;i<9;++i) Rp[i]=R12[i]; Pp[0]=P12[0];Pp[1]=P12[1];Pp[2]=P12[2]; }
        else              { for (int i=0;i<9;++i) Rp[i]=R[i];   Pp[0]=Pc[0];Pp[1]=Pc[1];Pp[2]=Pc[2]; }
        float T[9];
        float a[6] = {xb[j*6+0],xb[j*6+1],xb[j*6+2],xb[j*6+3],xb[j*6+4],xb[j*6+5]};
        rot6d(a, T);
        float o0=ob[j*3+0],o1=ob[j*3+1],o2=ob[j*3+2];
        Pc[0]=Rp[0]*o0+Rp[1]*o1+Rp[2]*o2+Pp[0];
        Pc[1]=Rp[3]*o0+Rp[4]*o1+Rp[5]*o2+Pp[1];
        Pc[2]=Rp[6]*o0+Rp[7]*o1+Rp[8]*o2+Pp[2];
        for (int i=0;i<3;++i) for (int k=0;k<3;++k) {
            float s=0.f; for (int m=0;m<3;++m) s+=Rp[i*3+m]*T[m*3+k];
            R[i*3+k]=s;
        }
        P[j*3+0]=Pc[0]; P[j*3+1]=Pc[1]; P[j*3+2]=Pc[2];
        if (j==11) { for (int i=0;i<9;++i) R11[i]=R[i]; P11[0]=Pc[0];P11[1]=Pc[1];P11[2]=Pc[2]; }
        if (j==12) { for (int i=0;i<9;++i) R12[i]=R[i]; P12[0]=Pc[0];P12[1]=Pc[1];P12[2]=Pc[2]; }
    }
}

extern "C" void kernel_launch(void* const* d_in, const int* in_sizes, int n_in,
                              void* d_out, int out_size, void* d_ws, size_t ws_size,
                              hipStream_t stream) {
    const float* x   = (const float*)d_in[0];
    const float* off = (const float*)d_in[2];
    float* out = (float*)d_out;
    int B = in_sizes[0] / 144;
    int ntiles = B / G;
    int nblk = (ntiles + 1) / 2;
    if (nblk > 0)
        fk_kernel<<<nblk, 256, 0, stream>>>(x, off, out, ntiles);
    int rem = B - ntiles * G;
    if (rem > 0)
        fk_tail<<<(rem + 255) / 256, 256, 0, stream>>>(x, off, out, ntiles * G, B);
}